// Round 17
// baseline (1068.457 us; speedup 1.0000x reference)
//
#include <hip/hip_runtime.h>
#include <hip/hip_fp16.h>

#define N_NODES 100000
#define N_GRAPHS 64
#define BN_EPS 1e-5

#define NB 782
#define NC 49
#define PT1 4096
#define PT2 2048
#define BPC 16
#define CAP 3072

__device__ __forceinline__ float bfly64(float v) {
#pragma unroll
    for (int m = 1; m < 64; m <<= 1) v += __shfl_xor(v, m, 64);
    return v;
}

__device__ __forceinline__ unsigned pack_h2(float a, float b) {
    __half2 h = __floats2half2_rn(a, b);
    unsigned w;
    __builtin_memcpy(&w, &h, 4);
    return w;
}

__device__ __forceinline__ float2 unpack_h2(unsigned w) {
    __half2 h;
    __builtin_memcpy(&h, &w, 4);
    return __half22float2(h);
}

// ---------------- pass 1: fine-bucket histogram ----------------
__global__ void hist_fine(const int* __restrict__ dst, int* __restrict__ bhist, int E) {
    __shared__ int h[NB];
    for (int i = threadIdx.x; i < NB; i += 256) h[i] = 0;
    __syncthreads();
    int stride = gridDim.x * 256;
    for (int e = blockIdx.x * 256 + threadIdx.x; e < E; e += stride) {
        int d = __builtin_nontemporal_load(dst + e);
        atomicAdd(&h[d >> 7], 1);
    }
    __syncthreads();
    for (int i = threadIdx.x; i < NB; i += 256)
        if (h[i]) atomicAdd(&bhist[i], h[i]);
}

// ---------------- pass 2: scan histogram -> offsets & cursors ----------------
__global__ void scan_buckets(const int* __restrict__ bhist, int* __restrict__ bo,
                             int* __restrict__ fcur, int* __restrict__ co,
                             int* __restrict__ ccur) {
    __shared__ int sh[1024];
    int t = threadIdx.x;
    sh[t] = (t < NB) ? bhist[t] : 0;
    __syncthreads();
    for (int st = 1; st < 1024; st <<= 1) {
        int v = (t >= st) ? sh[t - st] : 0;
        __syncthreads();
        sh[t] += v;
        __syncthreads();
    }
    int total = sh[NB - 1];
    if (t < NB) {
        int e = t ? sh[t - 1] : 0;
        bo[t] = e; fcur[t] = e;
    } else if (t < 784) {
        if (t == NB) bo[NB] = total;
        fcur[t] = total;
    }
    if (t < NC) {
        int i = t << 4;
        int e = i ? sh[i - 1] : 0;
        co[t] = e; ccur[t] = e;
    } else if (t == NC) {
        co[NC] = total;
    }
}

// ---------------- pass 3: coarse partition ----------------
__global__ __launch_bounds__(256)
void part1(const int* __restrict__ dst, const int* __restrict__ src,
           int* __restrict__ ccur, int* __restrict__ cdst, int* __restrict__ csrc, int E) {
    __shared__ int ld[PT1], ls[PT1];
    __shared__ unsigned char lb[PT1];
    __shared__ int hist[NC], lbase[NC], gbase[NC];
    long long t0 = (long long)blockIdx.x * PT1;
    int n = (int)min((long long)PT1, (long long)E - t0);
    int tid = threadIdx.x;
    for (int i = tid; i < NC; i += 256) hist[i] = 0;
    __syncthreads();
    int d[PT1 / 256], s[PT1 / 256], c[PT1 / 256];
#pragma unroll
    for (int k = 0; k < PT1 / 256; ++k) {
        int li = k * 256 + tid;
        if (li < n) {
            d[k] = __builtin_nontemporal_load(dst + t0 + li);
            s[k] = __builtin_nontemporal_load(src + t0 + li);
            c[k] = d[k] >> 11;
            atomicAdd(&hist[c[k]], 1);
        }
    }
    __syncthreads();
    if (tid == 0) {
        int run = 0;
        for (int i = 0; i < NC; ++i) { lbase[i] = run; run += hist[i]; }
    }
    __syncthreads();
    if (tid < NC) gbase[tid] = atomicAdd(&ccur[tid], hist[tid]);
    __syncthreads();
    for (int i = tid; i < NC; i += 256) hist[i] = 0;
    __syncthreads();
#pragma unroll
    for (int k = 0; k < PT1 / 256; ++k) {
        int li = k * 256 + tid;
        if (li < n) {
            int pos = lbase[c[k]] + atomicAdd(&hist[c[k]], 1);
            ld[pos] = d[k]; ls[pos] = s[k]; lb[pos] = (unsigned char)c[k];
        }
    }
    __syncthreads();
    for (int i = tid; i < n; i += 256) {
        int bb = lb[i];
        int g = gbase[bb] + (i - lbase[bb]);
        cdst[g] = ld[i];
        csrc[g] = ls[i];
    }
}

// ---------------- pass 4: fine partition ----------------
__global__ __launch_bounds__(256)
void part2(const int* __restrict__ cdst, const int* __restrict__ csrc,
           const int* __restrict__ co, int* __restrict__ fcur,
           int* __restrict__ qdst, int* __restrict__ qsrc) {
    __shared__ int ld[PT2], ls[PT2];
    __shared__ unsigned char lb[PT2];
    __shared__ int hist[16], lbase[16], gbase[16];
    int c = blockIdx.x / BPC;
    int j = blockIdx.x % BPC;
    int beg = co[c], end = co[c + 1];
    int tid = threadIdx.x;
    for (int t0 = beg + j * PT2; t0 < end; t0 += BPC * PT2) {
        int n = min(PT2, end - t0);
        if (tid < 16) hist[tid] = 0;
        __syncthreads();
        int d[PT2 / 256], s[PT2 / 256], f[PT2 / 256];
#pragma unroll
        for (int k = 0; k < PT2 / 256; ++k) {
            int li = k * 256 + tid;
            if (li < n) {
                d[k] = cdst[t0 + li];
                s[k] = csrc[t0 + li];
                f[k] = (d[k] >> 7) & 15;
                atomicAdd(&hist[f[k]], 1);
            }
        }
        __syncthreads();
        if (tid == 0) {
            int run = 0;
            for (int i = 0; i < 16; ++i) { lbase[i] = run; run += hist[i]; }
        }
        __syncthreads();
        if (tid < 16) gbase[tid] = atomicAdd(&fcur[(c << 4) + tid], hist[tid]);
        __syncthreads();
        if (tid < 16) hist[tid] = 0;
        __syncthreads();
#pragma unroll
        for (int k = 0; k < PT2 / 256; ++k) {
            int li = k * 256 + tid;
            if (li < n) {
                int pos = lbase[f[k]] + atomicAdd(&hist[f[k]], 1);
                ld[pos] = d[k]; ls[pos] = s[k]; lb[pos] = (unsigned char)f[k];
            }
        }
        __syncthreads();
        for (int i = tid; i < n; i += 256) {
            int bb = lb[i];
            int g = gbase[bb] + (i - lbase[bb]);
            qdst[g] = ld[i];
            qsrc[g] = ls[i];
        }
        __syncthreads();
    }
}

// ---------------- pass 5: per-bucket CSR finalize ----------------
__global__ __launch_bounds__(256)
void fill_final(const int* __restrict__ qdst, const int* __restrict__ qsrc,
                const int* __restrict__ bo, int* __restrict__ offs,
                int* __restrict__ nbr, int N, int E) {
    __shared__ int cnt[128], cbase[128], cur[128];
    __shared__ int lout[CAP];
    int b = blockIdx.x;
    int nlo = b << 7;
    int nn = min(128, N - nlo);
    int ebeg = bo[b], ne = bo[b + 1] - ebeg;
    int tid = threadIdx.x;
    if (tid < 128) { cnt[tid] = 0; cur[tid] = 0; }
    __syncthreads();
    for (int i = tid; i < ne; i += 256)
        atomicAdd(&cnt[qdst[ebeg + i] - nlo], 1);
    __syncthreads();
    if (tid < 128) cbase[tid] = cnt[tid];
    __syncthreads();
    for (int st = 1; st < 128; st <<= 1) {
        int v = 0;
        if (tid < 128 && tid >= st) v = cbase[tid - st];
        __syncthreads();
        if (tid < 128 && tid >= st) cbase[tid] += v;
        __syncthreads();
    }
    if (tid < nn)
        offs[nlo + tid] = ebeg + (tid ? cbase[tid - 1] : 0);
    if (b == NB - 1 && tid == 0) offs[N] = E;
    __syncthreads();
    for (int i = tid; i < ne; i += 256) {
        int d = qdst[ebeg + i];
        int s = qsrc[ebeg + i];
        int ln = d - nlo;
        int p = (ln ? cbase[ln - 1] : 0) + atomicAdd(&cur[ln], 1);
        lout[p] = s;
    }
    __syncthreads();
    for (int i = tid; i < ne; i += 256)
        nbr[ebeg + i] = lout[i];
}

// ---------------- layer 1 fused: agg + linear + BN stats; fp16 h1 out ----------------
__global__ __launch_bounds__(256)
void layer1_fused(const float2* __restrict__ x2,
                  const int* __restrict__ offs, const int* __restrict__ nbr,
                  const float* __restrict__ Wl, const float* __restrict__ bl,
                  const float* __restrict__ Wr,
                  __half* __restrict__ hout16,
                  double* __restrict__ sums, int N) {
    __shared__ float sAr[64];
    int tid = threadIdx.x;
    if (tid < 64) sAr[tid] = 0.f;
    __syncthreads();
    int n = blockIdx.x * 256 + tid;
    bool valid = (n < N);
    int beg = 0, end = 0;
    if (valid) { beg = offs[n]; end = offs[n + 1]; }
    double ax = 0.0, ay = 0.0;
    int j = beg;
    for (; j + 4 <= end; j += 4) {
        int s0 = nbr[j], s1 = nbr[j + 1], s2 = nbr[j + 2], s3 = nbr[j + 3];
        float2 v0 = x2[s0], v1 = x2[s1], v2 = x2[s2], v3 = x2[s3];
        ax += v0.x; ay += v0.y;
        ax += v1.x; ay += v1.y;
        ax += v2.x; ay += v2.y;
        ax += v3.x; ay += v3.y;
    }
    for (; j < end; ++j) {
        float2 v = x2[nbr[j]];
        ax += v.x; ay += v.y;
    }
    float invd = 1.0f / fmaxf((float)(end - beg), 1.0f);
    float a0 = (float)ax * invd, a1 = (float)ay * invd;
    float x0 = 0.f, x1 = 0.f;
    if (valid) {
        float2 xv = x2[n];
        x0 = xv.x; x1 = xv.y;
    }
    float acc[32];
#pragma unroll
    for (int jj = 0; jj < 32; ++jj)
        acc[jj] = bl[jj] + a0 * Wl[jj] + a1 * Wl[32 + jj] + x0 * Wr[jj] + x1 * Wr[32 + jj];
    if (valid) {
        unsigned w[16];
#pragma unroll
        for (int p = 0; p < 16; ++p) w[p] = pack_h2(acc[2*p], acc[2*p+1]);
        uint4* q = (uint4*)(hout16 + (size_t)n * 32);
        q[0] = make_uint4(w[0], w[1], w[2], w[3]);
        q[1] = make_uint4(w[4], w[5], w[6], w[7]);
        q[2] = make_uint4(w[8], w[9], w[10], w[11]);
        q[3] = make_uint4(w[12], w[13], w[14], w[15]);
    }
    int lane = tid & 63;
#pragma unroll
    for (int jj = 0; jj < 32; ++jj) {
        float v = valid ? acc[jj] : 0.f;
        float s = bfly64(v);
        float q = bfly64(v * v);
        if (lane == jj) atomicAdd(&sAr[jj], s);
        if (lane == 32 + jj) atomicAdd(&sAr[32 + jj], q);
    }
    __syncthreads();
    if (tid < 64) atomicAdd(&sums[tid], (double)sAr[tid]);
}

// ---------------- fp16 CSR gather agg -> fp16 agg out, inline BN finalize ----------------
template<int F>
__global__ __launch_bounds__(256)
void agg_h16(const uint2* __restrict__ xh, const int* __restrict__ offs,
             const int* __restrict__ nbr,
             const double* __restrict__ sums,
             const float* __restrict__ gamma, const float* __restrict__ beta,
             uint2* __restrict__ aggh, int N) {
    constexpr int FV = F / 4;
    constexpr int NPB = 256 / FV;
    __shared__ float lsc[F], lsf[F];
    int tid = threadIdx.y * FV + threadIdx.x;
    if (tid < F) {
        double mu = sums[tid] / (double)N_NODES;
        double var = sums[F + tid] / (double)N_NODES - mu * mu;
        if (var < 0.0) var = 0.0;
        double sc = (double)gamma[tid] / sqrt(var + BN_EPS);
        lsc[tid] = (float)sc;
        lsf[tid] = (float)((double)beta[tid] - mu * sc);
    }
    __syncthreads();
    int n = blockIdx.x * NPB + threadIdx.y;
    if (n >= N) return;
    int f = threadIdx.x;
    float4 sc = ((const float4*)lsc)[f];
    float4 sf = ((const float4*)lsf)[f];
    int beg = offs[n], end = offs[n + 1];
    double ax = 0.0, ay = 0.0, az = 0.0, aw = 0.0;
    int j = beg;
    for (; j + 8 <= end; j += 8) {
        int s[8];
#pragma unroll
        for (int u = 0; u < 8; ++u) s[u] = __builtin_nontemporal_load(nbr + j + u);
        uint2 uv[8];
#pragma unroll
        for (int u = 0; u < 8; ++u) uv[u] = xh[(long long)s[u] * FV + f];
#pragma unroll
        for (int u = 0; u < 8; ++u) {
            float2 f0 = unpack_h2(uv[u].x);
            float2 f1 = unpack_h2(uv[u].y);
            ax += fmaxf(f0.x * sc.x + sf.x, 0.f);
            ay += fmaxf(f0.y * sc.y + sf.y, 0.f);
            az += fmaxf(f1.x * sc.z + sf.z, 0.f);
            aw += fmaxf(f1.y * sc.w + sf.w, 0.f);
        }
    }
    for (; j + 4 <= end; j += 4) {
        int s[4];
#pragma unroll
        for (int u = 0; u < 4; ++u) s[u] = __builtin_nontemporal_load(nbr + j + u);
        uint2 uv[4];
#pragma unroll
        for (int u = 0; u < 4; ++u) uv[u] = xh[(long long)s[u] * FV + f];
#pragma unroll
        for (int u = 0; u < 4; ++u) {
            float2 f0 = unpack_h2(uv[u].x);
            float2 f1 = unpack_h2(uv[u].y);
            ax += fmaxf(f0.x * sc.x + sf.x, 0.f);
            ay += fmaxf(f0.y * sc.y + sf.y, 0.f);
            az += fmaxf(f1.x * sc.z + sf.z, 0.f);
            aw += fmaxf(f1.y * sc.w + sf.w, 0.f);
        }
    }
    for (; j < end; ++j) {
        int s = __builtin_nontemporal_load(nbr + j);
        uint2 uv = xh[(long long)s * FV + f];
        float2 f0 = unpack_h2(uv.x);
        float2 f1 = unpack_h2(uv.y);
        ax += fmaxf(f0.x * sc.x + sf.x, 0.f);
        ay += fmaxf(f0.y * sc.y + sf.y, 0.f);
        az += fmaxf(f1.x * sc.z + sf.z, 0.f);
        aw += fmaxf(f1.y * sc.w + sf.w, 0.f);
    }
    uint2 out;
    out.x = pack_h2((float)ax, (float)ay);
    out.y = pack_h2((float)az, (float)aw);
    aggh[(long long)n * FV + f] = out;
}

// ---------------- tiled linear: fp16 in (agg + x), fp32 compute, fp16 out ----------------
template<int DIN, int DOUT, int TN>
__global__ __launch_bounds__(256)
void linear_t2(const __half* __restrict__ xin16, const __half* __restrict__ agg16,
               const int* __restrict__ offs,
               const float* __restrict__ Wl, const float* __restrict__ bl,
               const float* __restrict__ Wr,
               const double* __restrict__ sumsIn,
               const float* __restrict__ gIn, const float* __restrict__ beIn,
               __half* __restrict__ hout16, int N) {
    constexpr int JT = 32;
    constexpr int NG = DOUT / JT;
    static_assert(TN * NG == 256, "cfg");
    constexpr int STRIDE = DIN + 1;
    constexpr int DIV4 = DIN / 4;
    constexpr int NV4 = TN * DIN / 4;
    __shared__ float shT[TN * STRIDE];
    __shared__ float shD[TN];
    __shared__ float lscIn[DIN], lsfIn[DIN];

    int tid = threadIdx.x;
    if (tid < DIN) {
        double mu = sumsIn[tid] / (double)N_NODES;
        double var = sumsIn[DIN + tid] / (double)N_NODES - mu * mu;
        if (var < 0.0) var = 0.0;
        double sc = (double)gIn[tid] / sqrt(var + BN_EPS);
        lscIn[tid] = (float)sc;
        lsfIn[tid] = (float)((double)beIn[tid] - mu * sc);
    }

    int n0 = blockIdx.x * TN;
    const uint2* __restrict__ gA = (const uint2*)(agg16 + (size_t)n0 * DIN);
#pragma unroll
    for (int it = 0; it < NV4 / 256; ++it) {
        int i = it * 256 + tid;
        int row = i / DIV4, col = (i % DIV4) * 4;
        uint2 uv = gA[i];
        float2 f0 = unpack_h2(uv.x);
        float2 f1 = unpack_h2(uv.y);
        float* p = &shT[row * STRIDE + col];
        p[0] = f0.x; p[1] = f0.y; p[2] = f1.x; p[3] = f1.y;
    }
    for (int i = tid; i < TN; i += 256) {
        int nn = min(n0 + i, N - 1);
        shD[i] = 1.0f / fmaxf((float)(offs[nn + 1] - offs[nn]), 1.0f);
    }
    __syncthreads();

    int tn = tid % TN;
    int jg = __builtin_amdgcn_readfirstlane(tid / TN);
    float invd = shD[tn];
    float acc[JT];
#pragma unroll
    for (int j = 0; j < JT; ++j) acc[j] = bl[jg * JT + j];

#pragma unroll 4
    for (int k = 0; k < DIN; ++k) {
        float a = shT[tn * STRIDE + k] * invd;
        const float* __restrict__ wlp = Wl + (size_t)k * DOUT + jg * JT;
#pragma unroll
        for (int j = 0; j < JT; ++j) acc[j] += a * wlp[j];
    }
    __syncthreads();

    const uint2* __restrict__ gX = (const uint2*)(xin16 + (size_t)n0 * DIN);
#pragma unroll
    for (int it = 0; it < NV4 / 256; ++it) {
        int i = it * 256 + tid;
        int row = i / DIV4, col4 = i % DIV4;
        uint2 uv = gX[i];
        float2 f0 = unpack_h2(uv.x);
        float2 f1 = unpack_h2(uv.y);
        float4 sc = ((const float4*)lscIn)[col4];
        float4 sf = ((const float4*)lsfIn)[col4];
        float* q = &shT[row * STRIDE + col4 * 4];
        q[0] = fmaxf(f0.x * sc.x + sf.x, 0.f);
        q[1] = fmaxf(f0.y * sc.y + sf.y, 0.f);
        q[2] = fmaxf(f1.x * sc.z + sf.z, 0.f);
        q[3] = fmaxf(f1.y * sc.w + sf.w, 0.f);
    }
    __syncthreads();

#pragma unroll 4
    for (int k = 0; k < DIN; ++k) {
        float xv = shT[tn * STRIDE + k];
        const float* __restrict__ wrp = Wr + (size_t)k * DOUT + jg * JT;
#pragma unroll
        for (int j = 0; j < JT; ++j) acc[j] += xv * wrp[j];
    }

    if (n0 + tn < N) {
        unsigned w[16];
#pragma unroll
        for (int p = 0; p < 16; ++p) w[p] = pack_h2(acc[2*p], acc[2*p+1]);
        uint4* qh = (uint4*)(hout16 + (size_t)(n0 + tn) * DOUT + jg * JT);
        qh[0] = make_uint4(w[0], w[1], w[2], w[3]);
        qh[1] = make_uint4(w[4], w[5], w[6], w[7]);
        qh[2] = make_uint4(w[8], w[9], w[10], w[11]);
        qh[3] = make_uint4(w[12], w[13], w[14], w[15]);
    }
}

// ---------------- BN stats v2: uint4 loads (8 features/thread), LDS tree, 2048 blocks ----------------
template<int F>
__global__ __launch_bounds__(256)
void bn_stats_v2(const uint4* __restrict__ h, double* __restrict__ sums, int N) {
    constexpr int P4 = F / 8;          // uint4 per row
    constexpr int R = 256 / P4;        // rows in flight per block
    __shared__ float sh[4096];         // [0,2048): sums, [2048,4096): sumsq (tid*8+j)
    int tid = threadIdx.x;
    int p = tid % P4;
    int r = tid / P4;
    float s[8], q[8];
#pragma unroll
    for (int j = 0; j < 8; ++j) { s[j] = 0.f; q[j] = 0.f; }
    for (int n = blockIdx.x * R + r; n < N; n += gridDim.x * R) {
        uint4 v = h[(size_t)n * P4 + p];
        float2 a = unpack_h2(v.x), b = unpack_h2(v.y), c = unpack_h2(v.z), d = unpack_h2(v.w);
        s[0] += a.x; q[0] += a.x * a.x;
        s[1] += a.y; q[1] += a.y * a.y;
        s[2] += b.x; q[2] += b.x * b.x;
        s[3] += b.y; q[3] += b.y * b.y;
        s[4] += c.x; q[4] += c.x * c.x;
        s[5] += c.y; q[5] += c.y * c.y;
        s[6] += d.x; q[6] += d.x * d.x;
        s[7] += d.y; q[7] += d.y * d.y;
    }
#pragma unroll
    for (int j = 0; j < 8; ++j) {
        sh[tid * 8 + j] = s[j];
        sh[2048 + tid * 8 + j] = q[j];
    }
    __syncthreads();
    for (int st = R / 2; st > 0; st >>= 1) {
        if (r < st) {
#pragma unroll
            for (int j = 0; j < 8; ++j) {
                sh[tid * 8 + j] += sh[(tid + st * P4) * 8 + j];
                sh[2048 + tid * 8 + j] += sh[2048 + (tid + st * P4) * 8 + j];
            }
        }
        __syncthreads();
    }
    if (r == 0) {
#pragma unroll
        for (int j = 0; j < 8; ++j) {
            atomicAdd(&sums[p * 8 + j], (double)sh[tid * 8 + j]);
            atomicAdd(&sums[F + p * 8 + j], (double)sh[2048 + tid * 8 + j]);
        }
    }
}

// ---------------- pool (fp16 h3) with inline BN3 finalize + fused ReLU ----------------
__global__ void pool_partial(const __half* __restrict__ h, const int* __restrict__ batch,
                             const double* __restrict__ sums,
                             const float* __restrict__ gamma, const float* __restrict__ beta,
                             double* __restrict__ pooled_d, int N) {
    __shared__ float lsc[128], lsf[128];
    const int CH = 64;
    int f = threadIdx.x;
    {
        double mu = sums[f] / (double)N_NODES;
        double var = sums[128 + f] / (double)N_NODES - mu * mu;
        if (var < 0.0) var = 0.0;
        double sc = (double)gamma[f] / sqrt(var + BN_EPS);
        lsc[f] = (float)sc;
        lsf[f] = (float)((double)beta[f] - mu * sc);
    }
    __syncthreads();
    int n0 = blockIdx.x * CH;
    if (n0 >= N) return;
    int n1 = min(n0 + CH, N);
    float sc = lsc[f], sf = lsf[f];
    int g = batch[n0];
    float acc = 0.f;
    for (int n = n0; n < n1; ++n) {
        int bg = batch[n];
        if (bg != g) {
            atomicAdd(&pooled_d[g * 128 + f], (double)acc);
            acc = 0.f;
            g = bg;
        }
        float v = __half2float(h[(long long)n * 128 + f]);
        acc += fmaxf(v * sc + sf, 0.f);
    }
    atomicAdd(&pooled_d[g * 128 + f], (double)acc);
}

// ---------------- fused pool-finalize + head MLP ----------------
__global__ void mlp_fused(const double* __restrict__ pooled_d, const int* __restrict__ batch,
                          const float* __restrict__ Wf1, const float* __restrict__ bf1,
                          const float* __restrict__ Wf2, const float* __restrict__ bf2,
                          float* __restrict__ out, int N) {
    __shared__ float sp[128];
    int g = blockIdx.x;
    int t = threadIdx.x;
    int lo = 0, hi = N;
    while (lo < hi) { int m = (lo + hi) >> 1; if (batch[m] < g) lo = m + 1; else hi = m; }
    int start = lo;
    hi = N;
    while (lo < hi) { int m = (lo + hi) >> 1; if (batch[m] < g + 1) lo = m + 1; else hi = m; }
    int cnt = lo - start;
    sp[t] = (float)(pooled_d[g * 128 + t] / (double)max(cnt, 1));
    __syncthreads();
    if (t < 64) {
        float hacc = bf1[t];
#pragma unroll 8
        for (int k = 0; k < 128; ++k) hacc += sp[k] * Wf1[k * 64 + t];
        hacc = fmaxf(hacc, 0.f) * Wf2[t];
        for (int o = 32; o > 0; o >>= 1) hacc += __shfl_down(hacc, o);
        if (t == 0) out[g] = hacc + bf2[0];
    }
}

extern "C" void kernel_launch(void* const* d_in, const int* in_sizes, int n_in,
                              void* d_out, int out_size, void* d_ws, size_t ws_size,
                              hipStream_t stream) {
    const float* x     = (const float*)d_in[0];
    const int*   ei    = (const int*)d_in[1];
    const int*   batch = (const int*)d_in[2];
    const float *Wl1=(const float*)d_in[3],  *bl1=(const float*)d_in[4],  *Wr1=(const float*)d_in[5];
    const float *g1 =(const float*)d_in[6],  *be1=(const float*)d_in[7];
    const float *Wl2=(const float*)d_in[8],  *bl2=(const float*)d_in[9],  *Wr2=(const float*)d_in[10];
    const float *g2 =(const float*)d_in[11], *be2=(const float*)d_in[12];
    const float *Wl3=(const float*)d_in[13], *bl3=(const float*)d_in[14], *Wr3=(const float*)d_in[15];
    const float *g3 =(const float*)d_in[16], *be3=(const float*)d_in[17];
    const float *Wf1=(const float*)d_in[18], *bf1=(const float*)d_in[19];
    const float *Wf2=(const float*)d_in[20], *bf2=(const float*)d_in[21];

    const int N = N_NODES;
    const int E = in_sizes[1] / 2;
    const int* src = ei;
    const int* dst = ei + E;

    char* ws = (char*)d_ws;
    size_t off = 0;
    auto salloc = [&](size_t bytes) {
        void* p = ws + off;
        off += (bytes + 255) & ~(size_t)255;
        return p;
    };
    // --- zero-init region (one memset) ---
    int*    bhist   = (int*)   salloc(NB * 4);
    double* sums    = (double*)salloc(768 * 8);
    double* pooledd = (double*)salloc((size_t)N_GRAPHS * 128 * 8);
    size_t zero_bytes = off;
    // --- rest ---
    int*    offs    = (int*)   salloc((size_t)(N + 1) * 4);
    int*    bo      = (int*)   salloc((NB + 1) * 4);
    int*    fcur    = (int*)   salloc(784 * 4);
    int*    co      = (int*)   salloc((NC + 1) * 4);
    int*    ccur    = (int*)   salloc(NC * 4);
    int*    nbr     = (int*)   salloc((size_t)E * 4);
    __half* h1h     = (__half*)salloc((size_t)(N + 256) * 32 * 2);   // 6.4 MB
    __half* h2h     = (__half*)salloc((size_t)(N + 256) * 64 * 2);   // 12.8 MB
    __half* h3h     = (__half*)salloc((size_t)(N + 256) * 128 * 2);  // 25.7 MB (hosts cdst/csrc early)
    __half* aggh    = (__half*)salloc((size_t)(N + 256) * 64 * 2);   // 12.8 MB (hosts qdst/qsrc early)
    (void)ws_size;

    double* sums1 = sums, *sums2 = sums + 256, *sums3 = sums + 512;
    int* cdst = (int*)h3h;
    int* csrc = cdst + E;
    int* qdst = (int*)aggh;
    int* qsrc = qdst + E;

    hipMemsetAsync(bhist, 0, zero_bytes, stream);

    // ---- CSR build ----
    hist_fine<<<1024, 256, 0, stream>>>(dst, bhist, E);
    scan_buckets<<<1, 1024, 0, stream>>>(bhist, bo, fcur, co, ccur);
    part1<<<(E + PT1 - 1) / PT1, 256, 0, stream>>>(dst, src, ccur, cdst, csrc, E);
    part2<<<NC * BPC, 256, 0, stream>>>(cdst, csrc, co, fcur, qdst, qsrc);
    fill_final<<<NB, 256, 0, stream>>>(qdst, qsrc, bo, offs, nbr, N, E);

    const int NL = (N + 255) / 256;

    // ---- layer 1: fused agg + linear + stats -> fp16 h1 ----
    layer1_fused<<<NL, 256, 0, stream>>>((const float2*)x, offs, nbr,
                                          Wl1, bl1, Wr1, h1h, sums1, N);

    // ---- layer 2 ----
    agg_h16<32><<<(N + 31) / 32, dim3(8, 32), 0, stream>>>(
        (const uint2*)h1h, offs, nbr, sums1, g1, be1, (uint2*)aggh, N);
    linear_t2<32, 64, 128><<<(N + 127) / 128, 256, 0, stream>>>(
        h1h, aggh, offs, Wl2, bl2, Wr2, sums1, g1, be1, h2h, N);
    bn_stats_v2<64><<<2048, 256, 0, stream>>>((const uint4*)h2h, sums2, N);

    // ---- layer 3 ----
    agg_h16<64><<<(N + 15) / 16, dim3(16, 16), 0, stream>>>(
        (const uint2*)h2h, offs, nbr, sums2, g2, be2, (uint2*)aggh, N);
    linear_t2<64, 128, 64><<<(N + 63) / 64, 256, 0, stream>>>(
        h2h, aggh, offs, Wl3, bl3, Wr3, sums2, g2, be2, h3h, N);
    bn_stats_v2<128><<<2048, 256, 0, stream>>>((const uint4*)h3h, sums3, N);

    // ---- pool + head ----
    pool_partial<<<(N + 63) / 64, 128, 0, stream>>>(h3h, batch, sums3, g3, be3, pooledd, N);
    mlp_fused<<<N_GRAPHS, 128, 0, stream>>>(pooledd, batch, Wf1, bf1, Wf2, bf2, (float*)d_out, N);
}

// Round 18
// 374.726 us; speedup vs baseline: 2.8513x; 2.8513x over previous
//
#include <hip/hip_runtime.h>
#include <hip/hip_fp16.h>

#define N_NODES 100000
#define N_GRAPHS 64
#define BN_EPS 1e-5

#define NB 782
#define NC 49
#define PT1 4096
#define PT2 2048
#define BPC 16
#define CAP 3072

__device__ __forceinline__ float bfly64(float v) {
#pragma unroll
    for (int m = 1; m < 64; m <<= 1) v += __shfl_xor(v, m, 64);
    return v;
}

__device__ __forceinline__ unsigned pack_h2(float a, float b) {
    __half2 h = __floats2half2_rn(a, b);
    unsigned w;
    __builtin_memcpy(&w, &h, 4);
    return w;
}

__device__ __forceinline__ float2 unpack_h2(unsigned w) {
    __half2 h;
    __builtin_memcpy(&h, &w, 4);
    return __half22float2(h);
}

// ---------------- pass 1: fine-bucket histogram ----------------
__global__ void hist_fine(const int* __restrict__ dst, int* __restrict__ bhist, int E) {
    __shared__ int h[NB];
    for (int i = threadIdx.x; i < NB; i += 256) h[i] = 0;
    __syncthreads();
    int stride = gridDim.x * 256;
    for (int e = blockIdx.x * 256 + threadIdx.x; e < E; e += stride) {
        int d = __builtin_nontemporal_load(dst + e);
        atomicAdd(&h[d >> 7], 1);
    }
    __syncthreads();
    for (int i = threadIdx.x; i < NB; i += 256)
        if (h[i]) atomicAdd(&bhist[i], h[i]);
}

// ---------------- pass 2: scan histogram -> offsets & cursors ----------------
__global__ void scan_buckets(const int* __restrict__ bhist, int* __restrict__ bo,
                             int* __restrict__ fcur, int* __restrict__ co,
                             int* __restrict__ ccur) {
    __shared__ int sh[1024];
    int t = threadIdx.x;
    sh[t] = (t < NB) ? bhist[t] : 0;
    __syncthreads();
    for (int st = 1; st < 1024; st <<= 1) {
        int v = (t >= st) ? sh[t - st] : 0;
        __syncthreads();
        sh[t] += v;
        __syncthreads();
    }
    int total = sh[NB - 1];
    if (t < NB) {
        int e = t ? sh[t - 1] : 0;
        bo[t] = e; fcur[t] = e;
    } else if (t < 784) {
        if (t == NB) bo[NB] = total;
        fcur[t] = total;
    }
    if (t < NC) {
        int i = t << 4;
        int e = i ? sh[i - 1] : 0;
        co[t] = e; ccur[t] = e;
    } else if (t == NC) {
        co[NC] = total;
    }
}

// ---------------- pass 3: coarse partition ----------------
__global__ __launch_bounds__(256)
void part1(const int* __restrict__ dst, const int* __restrict__ src,
           int* __restrict__ ccur, int* __restrict__ cdst, int* __restrict__ csrc, int E) {
    __shared__ int ld[PT1], ls[PT1];
    __shared__ unsigned char lb[PT1];
    __shared__ int hist[NC], lbase[NC], gbase[NC];
    long long t0 = (long long)blockIdx.x * PT1;
    int n = (int)min((long long)PT1, (long long)E - t0);
    int tid = threadIdx.x;
    for (int i = tid; i < NC; i += 256) hist[i] = 0;
    __syncthreads();
    int d[PT1 / 256], s[PT1 / 256], c[PT1 / 256];
#pragma unroll
    for (int k = 0; k < PT1 / 256; ++k) {
        int li = k * 256 + tid;
        if (li < n) {
            d[k] = __builtin_nontemporal_load(dst + t0 + li);
            s[k] = __builtin_nontemporal_load(src + t0 + li);
            c[k] = d[k] >> 11;
            atomicAdd(&hist[c[k]], 1);
        }
    }
    __syncthreads();
    if (tid == 0) {
        int run = 0;
        for (int i = 0; i < NC; ++i) { lbase[i] = run; run += hist[i]; }
    }
    __syncthreads();
    if (tid < NC) gbase[tid] = atomicAdd(&ccur[tid], hist[tid]);
    __syncthreads();
    for (int i = tid; i < NC; i += 256) hist[i] = 0;
    __syncthreads();
#pragma unroll
    for (int k = 0; k < PT1 / 256; ++k) {
        int li = k * 256 + tid;
        if (li < n) {
            int pos = lbase[c[k]] + atomicAdd(&hist[c[k]], 1);
            ld[pos] = d[k]; ls[pos] = s[k]; lb[pos] = (unsigned char)c[k];
        }
    }
    __syncthreads();
    for (int i = tid; i < n; i += 256) {
        int bb = lb[i];
        int g = gbase[bb] + (i - lbase[bb]);
        cdst[g] = ld[i];
        csrc[g] = ls[i];
    }
}

// ---------------- pass 4: fine partition ----------------
__global__ __launch_bounds__(256)
void part2(const int* __restrict__ cdst, const int* __restrict__ csrc,
           const int* __restrict__ co, int* __restrict__ fcur,
           int* __restrict__ qdst, int* __restrict__ qsrc) {
    __shared__ int ld[PT2], ls[PT2];
    __shared__ unsigned char lb[PT2];
    __shared__ int hist[16], lbase[16], gbase[16];
    int c = blockIdx.x / BPC;
    int j = blockIdx.x % BPC;
    int beg = co[c], end = co[c + 1];
    int tid = threadIdx.x;
    for (int t0 = beg + j * PT2; t0 < end; t0 += BPC * PT2) {
        int n = min(PT2, end - t0);
        if (tid < 16) hist[tid] = 0;
        __syncthreads();
        int d[PT2 / 256], s[PT2 / 256], f[PT2 / 256];
#pragma unroll
        for (int k = 0; k < PT2 / 256; ++k) {
            int li = k * 256 + tid;
            if (li < n) {
                d[k] = cdst[t0 + li];
                s[k] = csrc[t0 + li];
                f[k] = (d[k] >> 7) & 15;
                atomicAdd(&hist[f[k]], 1);
            }
        }
        __syncthreads();
        if (tid == 0) {
            int run = 0;
            for (int i = 0; i < 16; ++i) { lbase[i] = run; run += hist[i]; }
        }
        __syncthreads();
        if (tid < 16) gbase[tid] = atomicAdd(&fcur[(c << 4) + tid], hist[tid]);
        __syncthreads();
        if (tid < 16) hist[tid] = 0;
        __syncthreads();
#pragma unroll
        for (int k = 0; k < PT2 / 256; ++k) {
            int li = k * 256 + tid;
            if (li < n) {
                int pos = lbase[f[k]] + atomicAdd(&hist[f[k]], 1);
                ld[pos] = d[k]; ls[pos] = s[k]; lb[pos] = (unsigned char)f[k];
            }
        }
        __syncthreads();
        for (int i = tid; i < n; i += 256) {
            int bb = lb[i];
            int g = gbase[bb] + (i - lbase[bb]);
            qdst[g] = ld[i];
            qsrc[g] = ls[i];
        }
        __syncthreads();
    }
}

// ---------------- pass 5: per-bucket CSR finalize ----------------
__global__ __launch_bounds__(256)
void fill_final(const int* __restrict__ qdst, const int* __restrict__ qsrc,
                const int* __restrict__ bo, int* __restrict__ offs,
                int* __restrict__ nbr, int N, int E) {
    __shared__ int cnt[128], cbase[128], cur[128];
    __shared__ int lout[CAP];
    int b = blockIdx.x;
    int nlo = b << 7;
    int nn = min(128, N - nlo);
    int ebeg = bo[b], ne = bo[b + 1] - ebeg;
    int tid = threadIdx.x;
    if (tid < 128) { cnt[tid] = 0; cur[tid] = 0; }
    __syncthreads();
    for (int i = tid; i < ne; i += 256)
        atomicAdd(&cnt[qdst[ebeg + i] - nlo], 1);
    __syncthreads();
    if (tid < 128) cbase[tid] = cnt[tid];
    __syncthreads();
    for (int st = 1; st < 128; st <<= 1) {
        int v = 0;
        if (tid < 128 && tid >= st) v = cbase[tid - st];
        __syncthreads();
        if (tid < 128 && tid >= st) cbase[tid] += v;
        __syncthreads();
    }
    if (tid < nn)
        offs[nlo + tid] = ebeg + (tid ? cbase[tid - 1] : 0);
    if (b == NB - 1 && tid == 0) offs[N] = E;
    __syncthreads();
    for (int i = tid; i < ne; i += 256) {
        int d = qdst[ebeg + i];
        int s = qsrc[ebeg + i];
        int ln = d - nlo;
        int p = (ln ? cbase[ln - 1] : 0) + atomicAdd(&cur[ln], 1);
        lout[p] = s;
    }
    __syncthreads();
    for (int i = tid; i < ne; i += 256)
        nbr[ebeg + i] = lout[i];
}

// ---------------- layer 1 fused: agg + linear + BN stats; fp16 h1 out ----------------
__global__ __launch_bounds__(256)
void layer1_fused(const float2* __restrict__ x2,
                  const int* __restrict__ offs, const int* __restrict__ nbr,
                  const float* __restrict__ Wl, const float* __restrict__ bl,
                  const float* __restrict__ Wr,
                  __half* __restrict__ hout16,
                  double* __restrict__ sums, int N) {
    __shared__ float sAr[64];
    int tid = threadIdx.x;
    if (tid < 64) sAr[tid] = 0.f;
    __syncthreads();
    int n = blockIdx.x * 256 + tid;
    bool valid = (n < N);
    int beg = 0, end = 0;
    if (valid) { beg = offs[n]; end = offs[n + 1]; }
    double ax = 0.0, ay = 0.0;
    int j = beg;
    for (; j + 4 <= end; j += 4) {
        int s0 = nbr[j], s1 = nbr[j + 1], s2 = nbr[j + 2], s3 = nbr[j + 3];
        float2 v0 = x2[s0], v1 = x2[s1], v2 = x2[s2], v3 = x2[s3];
        ax += v0.x; ay += v0.y;
        ax += v1.x; ay += v1.y;
        ax += v2.x; ay += v2.y;
        ax += v3.x; ay += v3.y;
    }
    for (; j < end; ++j) {
        float2 v = x2[nbr[j]];
        ax += v.x; ay += v.y;
    }
    float invd = 1.0f / fmaxf((float)(end - beg), 1.0f);
    float a0 = (float)ax * invd, a1 = (float)ay * invd;
    float x0 = 0.f, x1 = 0.f;
    if (valid) {
        float2 xv = x2[n];
        x0 = xv.x; x1 = xv.y;
    }
    float acc[32];
#pragma unroll
    for (int jj = 0; jj < 32; ++jj)
        acc[jj] = bl[jj] + a0 * Wl[jj] + a1 * Wl[32 + jj] + x0 * Wr[jj] + x1 * Wr[32 + jj];
    if (valid) {
        unsigned w[16];
#pragma unroll
        for (int p = 0; p < 16; ++p) w[p] = pack_h2(acc[2*p], acc[2*p+1]);
        uint4* q = (uint4*)(hout16 + (size_t)n * 32);
        q[0] = make_uint4(w[0], w[1], w[2], w[3]);
        q[1] = make_uint4(w[4], w[5], w[6], w[7]);
        q[2] = make_uint4(w[8], w[9], w[10], w[11]);
        q[3] = make_uint4(w[12], w[13], w[14], w[15]);
    }
    int lane = tid & 63;
#pragma unroll
    for (int jj = 0; jj < 32; ++jj) {
        float v = valid ? acc[jj] : 0.f;
        float s = bfly64(v);
        float q = bfly64(v * v);
        if (lane == jj) atomicAdd(&sAr[jj], s);
        if (lane == 32 + jj) atomicAdd(&sAr[32 + jj], q);
    }
    __syncthreads();
    if (tid < 64) atomicAdd(&sums[tid], (double)sAr[tid]);
}

// ---------------- fp16 CSR gather agg -> fp16 agg out, inline BN finalize ----------------
template<int F>
__global__ __launch_bounds__(256)
void agg_h16(const uint2* __restrict__ xh, const int* __restrict__ offs,
             const int* __restrict__ nbr,
             const double* __restrict__ sums,
             const float* __restrict__ gamma, const float* __restrict__ beta,
             uint2* __restrict__ aggh, int N) {
    constexpr int FV = F / 4;
    constexpr int NPB = 256 / FV;
    __shared__ float lsc[F], lsf[F];
    int tid = threadIdx.y * FV + threadIdx.x;
    if (tid < F) {
        double mu = sums[tid] / (double)N_NODES;
        double var = sums[F + tid] / (double)N_NODES - mu * mu;
        if (var < 0.0) var = 0.0;
        double sc = (double)gamma[tid] / sqrt(var + BN_EPS);
        lsc[tid] = (float)sc;
        lsf[tid] = (float)((double)beta[tid] - mu * sc);
    }
    __syncthreads();
    int n = blockIdx.x * NPB + threadIdx.y;
    if (n >= N) return;
    int f = threadIdx.x;
    float4 sc = ((const float4*)lsc)[f];
    float4 sf = ((const float4*)lsf)[f];
    int beg = offs[n], end = offs[n + 1];
    double ax = 0.0, ay = 0.0, az = 0.0, aw = 0.0;
    int j = beg;
    for (; j + 8 <= end; j += 8) {
        int s[8];
#pragma unroll
        for (int u = 0; u < 8; ++u) s[u] = __builtin_nontemporal_load(nbr + j + u);
        uint2 uv[8];
#pragma unroll
        for (int u = 0; u < 8; ++u) uv[u] = xh[(long long)s[u] * FV + f];
#pragma unroll
        for (int u = 0; u < 8; ++u) {
            float2 f0 = unpack_h2(uv[u].x);
            float2 f1 = unpack_h2(uv[u].y);
            ax += fmaxf(f0.x * sc.x + sf.x, 0.f);
            ay += fmaxf(f0.y * sc.y + sf.y, 0.f);
            az += fmaxf(f1.x * sc.z + sf.z, 0.f);
            aw += fmaxf(f1.y * sc.w + sf.w, 0.f);
        }
    }
    for (; j + 4 <= end; j += 4) {
        int s[4];
#pragma unroll
        for (int u = 0; u < 4; ++u) s[u] = __builtin_nontemporal_load(nbr + j + u);
        uint2 uv[4];
#pragma unroll
        for (int u = 0; u < 4; ++u) uv[u] = xh[(long long)s[u] * FV + f];
#pragma unroll
        for (int u = 0; u < 4; ++u) {
            float2 f0 = unpack_h2(uv[u].x);
            float2 f1 = unpack_h2(uv[u].y);
            ax += fmaxf(f0.x * sc.x + sf.x, 0.f);
            ay += fmaxf(f0.y * sc.y + sf.y, 0.f);
            az += fmaxf(f1.x * sc.z + sf.z, 0.f);
            aw += fmaxf(f1.y * sc.w + sf.w, 0.f);
        }
    }
    for (; j < end; ++j) {
        int s = __builtin_nontemporal_load(nbr + j);
        uint2 uv = xh[(long long)s * FV + f];
        float2 f0 = unpack_h2(uv.x);
        float2 f1 = unpack_h2(uv.y);
        ax += fmaxf(f0.x * sc.x + sf.x, 0.f);
        ay += fmaxf(f0.y * sc.y + sf.y, 0.f);
        az += fmaxf(f1.x * sc.z + sf.z, 0.f);
        aw += fmaxf(f1.y * sc.w + sf.w, 0.f);
    }
    uint2 out;
    out.x = pack_h2((float)ax, (float)ay);
    out.y = pack_h2((float)az, (float)aw);
    aggh[(long long)n * FV + f] = out;
}

// ---------------- tiled linear: fp16 in (agg + x), fp32 compute, fp16 out ----------------
template<int DIN, int DOUT, int TN>
__global__ __launch_bounds__(256)
void linear_t2(const __half* __restrict__ xin16, const __half* __restrict__ agg16,
               const int* __restrict__ offs,
               const float* __restrict__ Wl, const float* __restrict__ bl,
               const float* __restrict__ Wr,
               const double* __restrict__ sumsIn,
               const float* __restrict__ gIn, const float* __restrict__ beIn,
               __half* __restrict__ hout16, int N) {
    constexpr int JT = 32;
    constexpr int NG = DOUT / JT;
    static_assert(TN * NG == 256, "cfg");
    constexpr int STRIDE = DIN + 1;
    constexpr int DIV4 = DIN / 4;
    constexpr int NV4 = TN * DIN / 4;
    __shared__ float shT[TN * STRIDE];
    __shared__ float shD[TN];
    __shared__ float lscIn[DIN], lsfIn[DIN];

    int tid = threadIdx.x;
    if (tid < DIN) {
        double mu = sumsIn[tid] / (double)N_NODES;
        double var = sumsIn[DIN + tid] / (double)N_NODES - mu * mu;
        if (var < 0.0) var = 0.0;
        double sc = (double)gIn[tid] / sqrt(var + BN_EPS);
        lscIn[tid] = (float)sc;
        lsfIn[tid] = (float)((double)beIn[tid] - mu * sc);
    }

    int n0 = blockIdx.x * TN;
    const uint2* __restrict__ gA = (const uint2*)(agg16 + (size_t)n0 * DIN);
#pragma unroll
    for (int it = 0; it < NV4 / 256; ++it) {
        int i = it * 256 + tid;
        int row = i / DIV4, col = (i % DIV4) * 4;
        uint2 uv = gA[i];
        float2 f0 = unpack_h2(uv.x);
        float2 f1 = unpack_h2(uv.y);
        float* p = &shT[row * STRIDE + col];
        p[0] = f0.x; p[1] = f0.y; p[2] = f1.x; p[3] = f1.y;
    }
    for (int i = tid; i < TN; i += 256) {
        int nn = min(n0 + i, N - 1);
        shD[i] = 1.0f / fmaxf((float)(offs[nn + 1] - offs[nn]), 1.0f);
    }
    __syncthreads();

    int tn = tid % TN;
    int jg = __builtin_amdgcn_readfirstlane(tid / TN);
    float invd = shD[tn];
    float acc[JT];
#pragma unroll
    for (int j = 0; j < JT; ++j) acc[j] = bl[jg * JT + j];

#pragma unroll 4
    for (int k = 0; k < DIN; ++k) {
        float a = shT[tn * STRIDE + k] * invd;
        const float* __restrict__ wlp = Wl + (size_t)k * DOUT + jg * JT;
#pragma unroll
        for (int j = 0; j < JT; ++j) acc[j] += a * wlp[j];
    }
    __syncthreads();

    const uint2* __restrict__ gX = (const uint2*)(xin16 + (size_t)n0 * DIN);
#pragma unroll
    for (int it = 0; it < NV4 / 256; ++it) {
        int i = it * 256 + tid;
        int row = i / DIV4, col4 = i % DIV4;
        uint2 uv = gX[i];
        float2 f0 = unpack_h2(uv.x);
        float2 f1 = unpack_h2(uv.y);
        float4 sc = ((const float4*)lscIn)[col4];
        float4 sf = ((const float4*)lsfIn)[col4];
        float* q = &shT[row * STRIDE + col4 * 4];
        q[0] = fmaxf(f0.x * sc.x + sf.x, 0.f);
        q[1] = fmaxf(f0.y * sc.y + sf.y, 0.f);
        q[2] = fmaxf(f1.x * sc.z + sf.z, 0.f);
        q[3] = fmaxf(f1.y * sc.w + sf.w, 0.f);
    }
    __syncthreads();

#pragma unroll 4
    for (int k = 0; k < DIN; ++k) {
        float xv = shT[tn * STRIDE + k];
        const float* __restrict__ wrp = Wr + (size_t)k * DOUT + jg * JT;
#pragma unroll
        for (int j = 0; j < JT; ++j) acc[j] += xv * wrp[j];
    }

    if (n0 + tn < N) {
        unsigned w[16];
#pragma unroll
        for (int p = 0; p < 16; ++p) w[p] = pack_h2(acc[2*p], acc[2*p+1]);
        uint4* qh = (uint4*)(hout16 + (size_t)(n0 + tn) * DOUT + jg * JT);
        qh[0] = make_uint4(w[0], w[1], w[2], w[3]);
        qh[1] = make_uint4(w[4], w[5], w[6], w[7]);
        qh[2] = make_uint4(w[8], w[9], w[10], w[11]);
        qh[3] = make_uint4(w[12], w[13], w[14], w[15]);
    }
}

// ---------------- BN stats, two-stage, NO global atomics ----------------
// Stage A: 1024 blocks; uint4 loads; per-wave shfl_xor reduce (feature const per thread);
// tiny LDS combine of 4 waves; one coalesced partial row per block.
template<int F>
__global__ __launch_bounds__(256)
void stats_partial(const uint4* __restrict__ h, float* __restrict__ partial, int N) {
    constexpr int P4 = F / 8;           // uint4 per row (8 or 16; power of two)
    constexpr int R = 256 / P4;         // rows in flight per block
    constexpr int NV = P4 * 16;         // values per wave-leader set (= 2F)
    __shared__ float lds[4 * NV];
    int tid = threadIdx.x;
    int p = tid % P4;
    int r = tid / P4;
    float s[8], q[8];
#pragma unroll
    for (int j = 0; j < 8; ++j) { s[j] = 0.f; q[j] = 0.f; }
    for (int n = blockIdx.x * R + r; n < N; n += 1024 * R) {
        uint4 v = h[(size_t)n * P4 + p];
        float2 a = unpack_h2(v.x), b = unpack_h2(v.y), c = unpack_h2(v.z), d = unpack_h2(v.w);
        s[0] += a.x; q[0] += a.x * a.x;
        s[1] += a.y; q[1] += a.y * a.y;
        s[2] += b.x; q[2] += b.x * b.x;
        s[3] += b.y; q[3] += b.y * b.y;
        s[4] += c.x; q[4] += c.x * c.x;
        s[5] += c.y; q[5] += c.y * c.y;
        s[6] += d.x; q[6] += d.x * d.x;
        s[7] += d.y; q[7] += d.y * d.y;
    }
    // reduce across lanes sharing p (lane stride P4) via xor-butterfly
    for (int m = P4; m < 64; m <<= 1) {
#pragma unroll
        for (int j = 0; j < 8; ++j) {
            s[j] += __shfl_xor(s[j], m, 64);
            q[j] += __shfl_xor(q[j], m, 64);
        }
    }
    int wave = tid >> 6;
    int lane = tid & 63;
    if (lane < P4) {
#pragma unroll
        for (int j = 0; j < 8; ++j) {
            lds[wave * NV + lane * 16 + j] = s[j];
            lds[wave * NV + lane * 16 + 8 + j] = q[j];
        }
    }
    __syncthreads();
    // combine 4 waves, write one coalesced partial row
    for (int v = tid; v < NV; v += 256) {
        float t0 = lds[v] + lds[NV + v] + lds[2 * NV + v] + lds[3 * NV + v];
        int pp = v >> 4, k = v & 15;
        int feat = pp * 8 + (k & 7);
        int out = (k < 8) ? feat : (F + feat);
        partial[(size_t)blockIdx.x * (2 * F) + out] = t0;
    }
}

// Stage B: 2F blocks; each block reduces 1024 partials for one output in fp64, fixed order.
template<int F>
__global__ __launch_bounds__(256)
void stats_finalize(const float* __restrict__ partial, double* __restrict__ sums) {
    __shared__ double sh[256];
    int i = blockIdx.x;
    int t = threadIdx.x;
    double a = 0.0;
#pragma unroll
    for (int k = 0; k < 4; ++k)
        a += (double)partial[(size_t)(t + k * 256) * (2 * F) + i];
    sh[t] = a;
    __syncthreads();
    for (int st = 128; st > 0; st >>= 1) {
        if (t < st) sh[t] += sh[t + st];
        __syncthreads();
    }
    if (t == 0) sums[i] = sh[0];
}

// ---------------- pool (fp16 h3) with inline BN3 finalize + fused ReLU ----------------
__global__ void pool_partial(const __half* __restrict__ h, const int* __restrict__ batch,
                             const double* __restrict__ sums,
                             const float* __restrict__ gamma, const float* __restrict__ beta,
                             double* __restrict__ pooled_d, int N) {
    __shared__ float lsc[128], lsf[128];
    const int CH = 64;
    int f = threadIdx.x;
    {
        double mu = sums[f] / (double)N_NODES;
        double var = sums[128 + f] / (double)N_NODES - mu * mu;
        if (var < 0.0) var = 0.0;
        double sc = (double)gamma[f] / sqrt(var + BN_EPS);
        lsc[f] = (float)sc;
        lsf[f] = (float)((double)beta[f] - mu * sc);
    }
    __syncthreads();
    int n0 = blockIdx.x * CH;
    if (n0 >= N) return;
    int n1 = min(n0 + CH, N);
    float sc = lsc[f], sf = lsf[f];
    int g = batch[n0];
    float acc = 0.f;
    for (int n = n0; n < n1; ++n) {
        int bg = batch[n];
        if (bg != g) {
            atomicAdd(&pooled_d[g * 128 + f], (double)acc);
            acc = 0.f;
            g = bg;
        }
        float v = __half2float(h[(long long)n * 128 + f]);
        acc += fmaxf(v * sc + sf, 0.f);
    }
    atomicAdd(&pooled_d[g * 128 + f], (double)acc);
}

// ---------------- fused pool-finalize + head MLP ----------------
__global__ void mlp_fused(const double* __restrict__ pooled_d, const int* __restrict__ batch,
                          const float* __restrict__ Wf1, const float* __restrict__ bf1,
                          const float* __restrict__ Wf2, const float* __restrict__ bf2,
                          float* __restrict__ out, int N) {
    __shared__ float sp[128];
    int g = blockIdx.x;
    int t = threadIdx.x;
    int lo = 0, hi = N;
    while (lo < hi) { int m = (lo + hi) >> 1; if (batch[m] < g) lo = m + 1; else hi = m; }
    int start = lo;
    hi = N;
    while (lo < hi) { int m = (lo + hi) >> 1; if (batch[m] < g + 1) lo = m + 1; else hi = m; }
    int cnt = lo - start;
    sp[t] = (float)(pooled_d[g * 128 + t] / (double)max(cnt, 1));
    __syncthreads();
    if (t < 64) {
        float hacc = bf1[t];
#pragma unroll 8
        for (int k = 0; k < 128; ++k) hacc += sp[k] * Wf1[k * 64 + t];
        hacc = fmaxf(hacc, 0.f) * Wf2[t];
        for (int o = 32; o > 0; o >>= 1) hacc += __shfl_down(hacc, o);
        if (t == 0) out[g] = hacc + bf2[0];
    }
}

extern "C" void kernel_launch(void* const* d_in, const int* in_sizes, int n_in,
                              void* d_out, int out_size, void* d_ws, size_t ws_size,
                              hipStream_t stream) {
    const float* x     = (const float*)d_in[0];
    const int*   ei    = (const int*)d_in[1];
    const int*   batch = (const int*)d_in[2];
    const float *Wl1=(const float*)d_in[3],  *bl1=(const float*)d_in[4],  *Wr1=(const float*)d_in[5];
    const float *g1 =(const float*)d_in[6],  *be1=(const float*)d_in[7];
    const float *Wl2=(const float*)d_in[8],  *bl2=(const float*)d_in[9],  *Wr2=(const float*)d_in[10];
    const float *g2 =(const float*)d_in[11], *be2=(const float*)d_in[12];
    const float *Wl3=(const float*)d_in[13], *bl3=(const float*)d_in[14], *Wr3=(const float*)d_in[15];
    const float *g3 =(const float*)d_in[16], *be3=(const float*)d_in[17];
    const float *Wf1=(const float*)d_in[18], *bf1=(const float*)d_in[19];
    const float *Wf2=(const float*)d_in[20], *bf2=(const float*)d_in[21];

    const int N = N_NODES;
    const int E = in_sizes[1] / 2;
    const int* src = ei;
    const int* dst = ei + E;

    char* ws = (char*)d_ws;
    size_t off = 0;
    auto salloc = [&](size_t bytes) {
        void* p = ws + off;
        off += (bytes + 255) & ~(size_t)255;
        return p;
    };
    // --- zero-init region (one memset) ---
    int*    bhist   = (int*)   salloc(NB * 4);
    double* sums    = (double*)salloc(768 * 8);
    double* pooledd = (double*)salloc((size_t)N_GRAPHS * 128 * 8);
    size_t zero_bytes = off;
    // --- rest ---
    int*    offs    = (int*)   salloc((size_t)(N + 1) * 4);
    int*    bo      = (int*)   salloc((NB + 1) * 4);
    int*    fcur    = (int*)   salloc(784 * 4);
    int*    co      = (int*)   salloc((NC + 1) * 4);
    int*    ccur    = (int*)   salloc(NC * 4);
    int*    nbr     = (int*)   salloc((size_t)E * 4);
    float*  partial = (float*) salloc((size_t)1024 * 256 * 4);       // 1 MB (stats partials)
    __half* h1h     = (__half*)salloc((size_t)(N + 256) * 32 * 2);   // 6.4 MB
    __half* h2h     = (__half*)salloc((size_t)(N + 256) * 64 * 2);   // 12.8 MB
    __half* h3h     = (__half*)salloc((size_t)(N + 256) * 128 * 2);  // 25.7 MB (hosts cdst/csrc early)
    __half* aggh    = (__half*)salloc((size_t)(N + 256) * 64 * 2);   // 12.8 MB (hosts qdst/qsrc early)
    (void)ws_size;

    double* sums1 = sums, *sums2 = sums + 256, *sums3 = sums + 512;
    int* cdst = (int*)h3h;
    int* csrc = cdst + E;
    int* qdst = (int*)aggh;
    int* qsrc = qdst + E;

    hipMemsetAsync(bhist, 0, zero_bytes, stream);

    // ---- CSR build ----
    hist_fine<<<1024, 256, 0, stream>>>(dst, bhist, E);
    scan_buckets<<<1, 1024, 0, stream>>>(bhist, bo, fcur, co, ccur);
    part1<<<(E + PT1 - 1) / PT1, 256, 0, stream>>>(dst, src, ccur, cdst, csrc, E);
    part2<<<NC * BPC, 256, 0, stream>>>(cdst, csrc, co, fcur, qdst, qsrc);
    fill_final<<<NB, 256, 0, stream>>>(qdst, qsrc, bo, offs, nbr, N, E);

    const int NL = (N + 255) / 256;

    // ---- layer 1: fused agg + linear + stats -> fp16 h1 ----
    layer1_fused<<<NL, 256, 0, stream>>>((const float2*)x, offs, nbr,
                                          Wl1, bl1, Wr1, h1h, sums1, N);

    // ---- layer 2 ----
    agg_h16<32><<<(N + 31) / 32, dim3(8, 32), 0, stream>>>(
        (const uint2*)h1h, offs, nbr, sums1, g1, be1, (uint2*)aggh, N);
    linear_t2<32, 64, 128><<<(N + 127) / 128, 256, 0, stream>>>(
        h1h, aggh, offs, Wl2, bl2, Wr2, sums1, g1, be1, h2h, N);
    stats_partial<64><<<1024, 256, 0, stream>>>((const uint4*)h2h, partial, N);
    stats_finalize<64><<<128, 256, 0, stream>>>(partial, sums2);

    // ---- layer 3 ----
    agg_h16<64><<<(N + 15) / 16, dim3(16, 16), 0, stream>>>(
        (const uint2*)h2h, offs, nbr, sums2, g2, be2, (uint2*)aggh, N);
    linear_t2<64, 128, 64><<<(N + 63) / 64, 256, 0, stream>>>(
        h2h, aggh, offs, Wl3, bl3, Wr3, sums2, g2, be2, h3h, N);
    stats_partial<128><<<1024, 256, 0, stream>>>((const uint4*)h3h, partial, N);
    stats_finalize<128><<<256, 256, 0, stream>>>(partial, sums3);

    // ---- pool + head ----
    pool_partial<<<(N + 63) / 64, 128, 0, stream>>>(h3h, batch, sums3, g3, be3, pooledd, N);
    mlp_fused<<<N_GRAPHS, 128, 0, stream>>>(pooledd, batch, Wf1, bf1, Wf2, bf2, (float*)d_out, N);
}